// Round 6
// baseline (4481241.797 us; speedup 1.0000x reference)
//
#include <hip/hip_runtime.h>

typedef __attribute__((ext_vector_type(4))) short bf4;
typedef __attribute__((ext_vector_type(8))) short bf8;
typedef __attribute__((ext_vector_type(4))) float f4;
typedef __attribute__((ext_vector_type(4))) unsigned u4;

#define BB 64
#define SS 512
#define II 512
#define HH 1024
#define SCH 64     // steps per chunk
#define NCH 8      // chunks

// flag region: per-XCD base = xcd*2048 dwords (8 KB apart)
#define FLAG_GO    192
#define FLAG_XCNT  132
#define FLAG_GINIT 16384

__device__ __forceinline__ short f2bf(float f) {
  unsigned u = __float_as_uint(f);
  u = u + 0x7fff + ((u >> 16) & 1);   // round-to-nearest-even
  return (short)(u >> 16);
}
__device__ __forceinline__ float bf2f(short s) {
  return __uint_as_float(((unsigned)(unsigned short)s) << 16);
}
__device__ __forceinline__ float sigm(float x) { return 1.0f / (1.0f + __expf(-x)); }
__device__ __forceinline__ float tanh_f(float x) {
  float e = __expf(-2.0f * fabsf(x));
  return copysignf((1.0f - e) / (1.0f + e), x);
}

union AFR { u4 u; bf8 v; };

// 8 consecutive 16-B A-fragment loads, L1-bypassed (sc0), 64-bit VGPR address form.
#define ALD8(A, ap) do {                                                                                  \
  asm volatile("global_load_dwordx4 %0, %1, off sc0"            : "=v"((A)[0].u) : "v"(ap) : "memory");   \
  asm volatile("global_load_dwordx4 %0, %1, off offset:64 sc0"  : "=v"((A)[1].u) : "v"(ap) : "memory");   \
  asm volatile("global_load_dwordx4 %0, %1, off offset:128 sc0" : "=v"((A)[2].u) : "v"(ap) : "memory");   \
  asm volatile("global_load_dwordx4 %0, %1, off offset:192 sc0" : "=v"((A)[3].u) : "v"(ap) : "memory");   \
  asm volatile("global_load_dwordx4 %0, %1, off offset:256 sc0" : "=v"((A)[4].u) : "v"(ap) : "memory");   \
  asm volatile("global_load_dwordx4 %0, %1, off offset:320 sc0" : "=v"((A)[5].u) : "v"(ap) : "memory");   \
  asm volatile("global_load_dwordx4 %0, %1, off offset:384 sc0" : "=v"((A)[6].u) : "v"(ap) : "memory");   \
  asm volatile("global_load_dwordx4 %0, %1, off offset:448 sc0" : "=v"((A)[7].u) : "v"(ap) : "memory");   \
} while (0)

#define AWAIT(A) asm volatile("s_waitcnt vmcnt(0)"                                \
  : "+v"((A)[0].u), "+v"((A)[1].u), "+v"((A)[2].u), "+v"((A)[3].u),               \
    "+v"((A)[4].u), "+v"((A)[5].u), "+v"((A)[6].u), "+v"((A)[7].u) :: "memory")

// bounded sc0 spin, 64-bit VGPR address form (works for divergent pointers)
__device__ __forceinline__ void spin_ge(const unsigned* p, unsigned target) {
  unsigned v; int it = 0;
  do {
    asm volatile("global_load_dword %0, %1, off sc0\n\ts_waitcnt vmcnt(0)"
                 : "=v"(v) : "v"(p) : "memory");
    if (v >= target) return;
    __builtin_amdgcn_s_sleep(1);
  } while (++it < 50000);   // bounded: wrong-visibility => fast wrong answer, not a hang
}

// intra-XCD barrier: plain stores -> own L2 (write-through L1); sc0 loads read back.
__device__ __forceinline__ void xbar(unsigned* F, int r, int P, unsigned target) {
  asm volatile("s_waitcnt vmcnt(0)" ::: "memory");   // drain this wave's data stores to L2
  __syncthreads();                                   // all waves drained
  if (threadIdx.x == 0) F[4 * r] = target;           // arrival slot (plain store)
  if (r == 0) {                                      // master block of this XCD
    if ((int)threadIdx.x < P) spin_ge(F + 4 * threadIdx.x, target);
    __syncthreads();
    if (threadIdx.x == 0) F[FLAG_GO] = target;
  }
  if (threadIdx.x == 0) spin_ge(F + FLAG_GO, target);
  __syncthreads();
}

// ---------------- prep kernels ----------------

__global__ __launch_bounds__(256) void prep_wxt_k(const float* __restrict__ Wz, const float* __restrict__ Wr,
                                                  const float* __restrict__ Wh, short* __restrict__ WxT) {
  int idx = blockIdx.x * 256 + threadIdx.x;           // < 3*1024*512
  int g = idx >> 19;
  int rem = idx & 524287;
  int n = rem >> 9, k = rem & 511;
  const float* W = (g == 0) ? Wz : (g == 1) ? Wr : Wh;
  WxT[idx] = f2bf(W[(size_t)k * HH + n]);
}

// Us[g][tile][kk][lane][j] = W_g[512 + kk*32 + (lane>>4)*8 + j][tile*16 + (lane&15)]
__global__ __launch_bounds__(256) void prep_uswz_k(const float* __restrict__ Wz, const float* __restrict__ Wr,
                                                   const float* __restrict__ Wh, short* __restrict__ Us) {
  int t = blockIdx.x * 256 + threadIdx.x;             // < 3*64*32*64
  int lane = t & 63, kk = (t >> 6) & 31, nb = (t >> 11) & 63, g = t >> 17;
  const float* W = (g == 0) ? Wz : (g == 1) ? Wr : Wh;
  int n = nb * 16 + (lane & 15);
  int kb = II + kk * 32 + (lane >> 4) * 8;
  bf8 o;
#pragma unroll
  for (int j = 0; j < 8; j++) o[j] = f2bf(W[(size_t)(kb + j) * HH + n]);
  *(bf8*)(Us + (size_t)t * 8) = o;
}

__global__ __launch_bounds__(256) void init_h_k(const float* __restrict__ h, float* __restrict__ h32) {
  int i = blockIdx.x * 256 + threadIdx.x;             // < 65536
  h32[i] = h[i];
}

// ---------------- input-projection GEMM (reads fp32 x directly) ----------------
__global__ __launch_bounds__(256) void gemm_k(const float* __restrict__ x, const short* __restrict__ WxT,
                                              const float* __restrict__ bz, const float* __restrict__ br,
                                              const float* __restrict__ bh, short* __restrict__ Gx, int s0) {
  __shared__ short Al[4 * 64 * 8];
  __shared__ short Bl[4 * 64 * 8];
  int tid = threadIdx.x, wave = tid >> 6, lane = tid & 63;
  int sl = blockIdx.x;
  int n0 = blockIdx.y * 64;
  f4 acc[4] = {};
  int mp = tid >> 2, q = tid & 3;
  const float* asrc = x + ((size_t)mp * SS + (s0 + sl)) * II + q * 8;   // fp32, convert on stage
  int ng = n0 + mp;
  int gb = ng >> 10, hb_ = ng & 1023;
  const short* bsrc = WxT + ((size_t)gb * HH + hb_) * II + q * 8;
  int adst = ((mp >> 4) * 64 + q * 16 + (mp & 15)) * 8;

  for (int kk = 0; kk < II; kk += 32) {
    float4 a0 = *(const float4*)(asrc + kk);
    float4 a1 = *(const float4*)(asrc + kk + 4);
    bf8 av;
    av[0] = f2bf(a0.x); av[1] = f2bf(a0.y); av[2] = f2bf(a0.z); av[3] = f2bf(a0.w);
    av[4] = f2bf(a1.x); av[5] = f2bf(a1.y); av[6] = f2bf(a1.z); av[7] = f2bf(a1.w);
    bf8 bv = *(const bf8*)(bsrc + kk);
    __syncthreads();
    *(bf8*)&Al[adst] = av;
    *(bf8*)&Bl[adst] = bv;
    __syncthreads();
    bf8 af = *(bf8*)&Al[(wave * 64 + lane) * 8];
#pragma unroll
    for (int ns = 0; ns < 4; ns++) {
      bf8 bfr = *(bf8*)&Bl[(ns * 64 + lane) * 8];
      acc[ns] = __builtin_amdgcn_mfma_f32_16x16x32_bf16(af, bfr, acc[ns], 0, 0, 0);
    }
  }
  int brow0 = wave * 16 + (lane >> 4) * 4;
#pragma unroll
  for (int ns = 0; ns < 4; ns++) {
    int ngl = n0 + ns * 16 + (lane & 15);
    int g2 = ngl >> 10, h2 = ngl & 1023;
    float bias = ((g2 == 0) ? bz : (g2 == 1) ? br : bh)[h2];
    bf4 o;
#pragma unroll
    for (int i = 0; i < 4; i++) o[i] = f2bf(acc[ns][i] + bias);
    *(bf4*)&Gx[(((size_t)sl * 3 + g2) * HH + h2) * BB + brow0] = o;
  }
}

// ---------------- XCD-replicated persistent recurrent kernel ----------------
// 256 blocks; each XCD's blocks redundantly compute the FULL h-update using only
// their own XCD's L2 (plain stores + sc0 loads). No cross-XCD traffic in the loop.

__global__ __launch_bounds__(256, 1) void rec_k(const short* __restrict__ Gx, const short* __restrict__ Us,
                                                float* __restrict__ h32, short* hbX, short* rhbX,
                                                unsigned* flags) {
  __shared__ short Uzr[32768];     // 64 KB: Uz,Ur fragments for FIRST owned tile
  __shared__ unsigned sh[2];
  int tid = threadIdx.x, wave = tid >> 6, lane = tid & 63;

  unsigned xcd;
  asm volatile("s_getreg_b32 %0, hwreg(HW_REG_XCC_ID)" : "=s"(xcd));
  xcd &= 7;
  unsigned* F = flags + xcd * 2048;

  // registration (once per launch, MALL atomics — known-working path). Bounded.
  if (tid == 0) {
    unsigned rr = __hip_atomic_fetch_add(&F[FLAG_XCNT], 1u, __ATOMIC_RELAXED, __HIP_MEMORY_SCOPE_AGENT);
    __hip_atomic_fetch_add(&flags[FLAG_GINIT], 1u, __ATOMIC_RELAXED, __HIP_MEMORY_SCOPE_AGENT);
    sh[0] = rr;
  }
  __syncthreads();
  int r = __builtin_amdgcn_readfirstlane(sh[0]);
  if (tid == 0) {
    int it = 0;
    while (__hip_atomic_load(&flags[FLAG_GINIT], __ATOMIC_RELAXED, __HIP_MEMORY_SCOPE_AGENT) < 256u
           && ++it < 2000000)
      __builtin_amdgcn_s_sleep(8);
    sh[1] = __hip_atomic_load(&F[FLAG_XCNT], __ATOMIC_RELAXED, __HIP_MEMORY_SCOPE_AGENT);
  }
  __syncthreads();
  int cnt = __builtin_amdgcn_readfirstlane(sh[1]);
  int P = cnt < 32 ? cnt : 32;
  if (r >= P) return;                               // non-participants exit

  // stage Uz/Ur fragments for first tile (tile index = r)
  {
    const bf8* sz = (const bf8*)Us + ((size_t)(0 * 64 + r)) * 2048;
    const bf8* sr = (const bf8*)Us + ((size_t)(1 * 64 + r)) * 2048;
    bf8* d = (bf8*)Uzr;
    for (int i = tid; i < 2048; i += 256) { d[i] = sz[i]; d[2048 + i] = sr[i]; }
  }

  int brow0 = wave * 16 + (lane >> 4) * 4;
  unsigned vo = (unsigned)((wave * 16 + (lane & 15)) * 2048 + (lane >> 4) * 16);  // A-frag byte offset
  short* hb0  = hbX  + ((size_t)(xcd * 2 + 0) << 16);
  short* hb1  = hbX  + ((size_t)(xcd * 2 + 1) << 16);
  short* rhb0 = rhbX + ((size_t)(xcd * 2 + 0) << 16);
  short* rhb1 = rhbX + ((size_t)(xcd * 2 + 1) << 16);

  float hreg[4][4], zf[4][4];
  // init fp32 state + publish bf16 h into parity-0 buffer
#pragma unroll
  for (int k = 0; k < 4; k++) {
    int t = r + k * P;
    if (t < 64) {
      int ncol = t * 16 + (lane & 15);
#pragma unroll
      for (int i = 0; i < 4; i++) {
        float v = h32[(size_t)(brow0 + i) * HH + ncol];
        hreg[k][i] = v;
        unsigned sv = (unsigned short)f2bf(v);
        unsigned up = __shfl_down(sv, 1);
        if (!(lane & 1)) *(unsigned*)(hb0 + (size_t)(brow0 + i) * HH + (ncol & ~1)) = sv | (up << 16);
      }
    }
  }
  unsigned target = 1;
  xbar(F, r, P, target);

  for (int t = 0; t < SCH; t++) {
    const short* hbp  = (t & 1) ? hb1 : hb0;
    short*       rhbp = (t & 1) ? rhb1 : rhb0;
    short*       hbn  = (t & 1) ? hb0 : hb1;
    const short* Gxt  = Gx + (size_t)t * 3 * HH * BB;

    // -------- phase 1: z, r --------
#pragma unroll
    for (int q = 0; q < 2; q++) {
      const int k0 = 2 * q, k1 = 2 * q + 1;
      int t0 = r + k0 * P;
      if (t0 < 64) {
        int t1 = r + k1 * P; bool v1 = (t1 < 64);
        f4 az0 = {}, ar0 = {}, az1 = {}, ar1 = {};
        AFR Aa[8], Ab[8];
        const char* ap = (const char*)hbp + vo;
        ALD8(Aa, ap);
#pragma unroll
        for (int g = 0; g < 4; g++) {
          AFR* C = (g & 1) ? Ab : Aa;
          AFR* N = (g & 1) ? Aa : Ab;
          AWAIT(C);
          if (g < 3) ALD8(N, ap + (g + 1) * 512);
#pragma unroll
          for (int j = 0; j < 8; j++) {
            int kk = g * 8 + j;
            bf8 af = C[j].v;
            bf8 b0z, b0r;
            if (q == 0) {
              b0z = *(bf8*)&Uzr[(kk * 64 + lane) * 8];
              b0r = *(bf8*)&Uzr[16384 + (kk * 64 + lane) * 8];
            } else {
              b0z = *(const bf8*)(Us + (((size_t)0 * 64 + t0) * 2048 + kk * 64 + lane) * 8);
              b0r = *(const bf8*)(Us + (((size_t)1 * 64 + t0) * 2048 + kk * 64 + lane) * 8);
            }
            az0 = __builtin_amdgcn_mfma_f32_16x16x32_bf16(af, b0z, az0, 0, 0, 0);
            ar0 = __builtin_amdgcn_mfma_f32_16x16x32_bf16(af, b0r, ar0, 0, 0, 0);
            if (v1) {
              bf8 b1z = *(const bf8*)(Us + (((size_t)0 * 64 + t1) * 2048 + kk * 64 + lane) * 8);
              bf8 b1r = *(const bf8*)(Us + (((size_t)1 * 64 + t1) * 2048 + kk * 64 + lane) * 8);
              az1 = __builtin_amdgcn_mfma_f32_16x16x32_bf16(af, b1z, az1, 0, 0, 0);
              ar1 = __builtin_amdgcn_mfma_f32_16x16x32_bf16(af, b1r, ar1, 0, 0, 0);
            }
          }
        }
        {
          int ncol = t0 * 16 + (lane & 15);
          const short* gp = Gxt + (size_t)ncol * BB + brow0;
          bf4 gzv = *(const bf4*)gp;
          bf4 grv = *(const bf4*)(gp + (size_t)HH * BB);
#pragma unroll
          for (int i = 0; i < 4; i++) {
            zf[k0][i] = sigm(az0[i] + bf2f(gzv[i]));
            float rr = sigm(ar0[i] + bf2f(grv[i]));
            unsigned sv = (unsigned short)f2bf(rr * hreg[k0][i]);
            unsigned up = __shfl_down(sv, 1);
            if (!(lane & 1)) *(unsigned*)(rhbp + (size_t)(brow0 + i) * HH + (ncol & ~1)) = sv | (up << 16);
          }
        }
        if (v1) {
          int ncol = t1 * 16 + (lane & 15);
          const short* gp = Gxt + (size_t)ncol * BB + brow0;
          bf4 gzv = *(const bf4*)gp;
          bf4 grv = *(const bf4*)(gp + (size_t)HH * BB);
#pragma unroll
          for (int i = 0; i < 4; i++) {
            zf[k1][i] = sigm(az1[i] + bf2f(gzv[i]));
            float rr = sigm(ar1[i] + bf2f(grv[i]));
            unsigned sv = (unsigned short)f2bf(rr * hreg[k1][i]);
            unsigned up = __shfl_down(sv, 1);
            if (!(lane & 1)) *(unsigned*)(rhbp + (size_t)(brow0 + i) * HH + (ncol & ~1)) = sv | (up << 16);
          }
        }
      }
    }
    xbar(F, r, P, ++target);

    // -------- phase 2: candidate + update --------
#pragma unroll
    for (int q = 0; q < 2; q++) {
      const int k0 = 2 * q, k1 = 2 * q + 1;
      int t0 = r + k0 * P;
      if (t0 < 64) {
        int t1 = r + k1 * P; bool v1 = (t1 < 64);
        f4 c0 = {}, c1 = {};
        AFR Aa[8], Ab[8];
        const char* ap = (const char*)rhbp + vo;
        ALD8(Aa, ap);
#pragma unroll
        for (int g = 0; g < 4; g++) {
          AFR* C = (g & 1) ? Ab : Aa;
          AFR* N = (g & 1) ? Aa : Ab;
          AWAIT(C);
          if (g < 3) ALD8(N, ap + (g + 1) * 512);
#pragma unroll
          for (int j = 0; j < 8; j++) {
            int kk = g * 8 + j;
            bf8 af = C[j].v;
            bf8 bh0 = *(const bf8*)(Us + (((size_t)2 * 64 + t0) * 2048 + kk * 64 + lane) * 8);
            c0 = __builtin_amdgcn_mfma_f32_16x16x32_bf16(af, bh0, c0, 0, 0, 0);
            if (v1) {
              bf8 bh1 = *(const bf8*)(Us + (((size_t)2 * 64 + t1) * 2048 + kk * 64 + lane) * 8);
              c1 = __builtin_amdgcn_mfma_f32_16x16x32_bf16(af, bh1, c1, 0, 0, 0);
            }
          }
        }
        {
          int ncol = t0 * 16 + (lane & 15);
          bf4 ghv = *(const bf4*)(Gxt + ((size_t)2 * HH + ncol) * BB + brow0);
#pragma unroll
          for (int i = 0; i < 4; i++) {
            float c = tanh_f(c0[i] + bf2f(ghv[i]));
            float hn = hreg[k0][i] + zf[k0][i] * (c - hreg[k0][i]);
            hreg[k0][i] = hn;
            unsigned sv = (unsigned short)f2bf(hn);
            unsigned up = __shfl_down(sv, 1);
            if (!(lane & 1)) *(unsigned*)(hbn + (size_t)(brow0 + i) * HH + (ncol & ~1)) = sv | (up << 16);
          }
        }
        if (v1) {
          int ncol = t1 * 16 + (lane & 15);
          bf4 ghv = *(const bf4*)(Gxt + ((size_t)2 * HH + ncol) * BB + brow0);
#pragma unroll
          for (int i = 0; i < 4; i++) {
            float c = tanh_f(c1[i] + bf2f(ghv[i]));
            float hn = hreg[k1][i] + zf[k1][i] * (c - hreg[k1][i]);
            hreg[k1][i] = hn;
            unsigned sv = (unsigned short)f2bf(hn);
            unsigned up = __shfl_down(sv, 1);
            if (!(lane & 1)) *(unsigned*)(hbn + (size_t)(brow0 + i) * HH + (ncol & ~1)) = sv | (up << 16);
          }
        }
      }
    }
    xbar(F, r, P, ++target);
  }

  // final fp32 state (duplicated identically across XCDs — benign, bit-identical)
#pragma unroll
  for (int k = 0; k < 4; k++) {
    int t = r + k * P;
    if (t < 64) {
      int ncol = t * 16 + (lane & 15);
#pragma unroll
      for (int i = 0; i < 4; i++) h32[(size_t)(brow0 + i) * HH + ncol] = hreg[k][i];
    }
  }
}

// ---------------- output head ----------------

__global__ __launch_bounds__(64) void out_k(const float* __restrict__ h32, const float* __restrict__ Wfc,
                                            const float* __restrict__ bfc, float* __restrict__ out) {
  int b = blockIdx.x, t = threadIdx.x;
  float a0 = 0.f, a1 = 0.f;
  for (int k = t; k < HH; k += 64) {
    float hv = fmaxf(h32[(size_t)b * HH + k], 0.f);
    a0 += hv * Wfc[k * 2]; a1 += hv * Wfc[k * 2 + 1];
  }
#pragma unroll
  for (int off = 32; off > 0; off >>= 1) { a0 += __shfl_down(a0, off); a1 += __shfl_down(a1, off); }
  if (t == 0) {
    float y0 = a0 + bfc[0], y1 = a1 + bfc[1];
    float m = fmaxf(y0, y1);
    float lse = m + logf(__expf(y0 - m) + __expf(y1 - m));
    out[b * 2] = y0 - lse; out[b * 2 + 1] = y1 - lse;
  }
}

// ---------------- launch ----------------

extern "C" void kernel_launch(void* const* d_in, const int* in_sizes, int n_in,
                              void* d_out, int out_size, void* d_ws, size_t ws_size,
                              hipStream_t stream) {
  const float* x   = (const float*)d_in[0];
  const float* h0  = (const float*)d_in[1];
  const float* Wz  = (const float*)d_in[2];
  const float* bz  = (const float*)d_in[3];
  const float* Wr  = (const float*)d_in[4];
  const float* br  = (const float*)d_in[5];
  const float* Wh  = (const float*)d_in[6];
  const float* bh  = (const float*)d_in[7];
  const float* Wfc = (const float*)d_in[8];
  const float* bfc = (const float*)d_in[9];
  float* out = (float*)d_out;

  // compact workspace: 39,126,016 B total (well under the proven 68.7 MB envelope)
  char* ws = (char*)d_ws;
  short*    WxT   = (short*)(ws);                       //  3,145,728 B
  short*    Us    = (short*)(ws + 3145728);             //  6,291,456 B
  short*    Gx    = (short*)(ws + 9437184);             // 25,165,824 B (one chunk)
  float*    h32   = (float*)(ws + 34603008);            //    262,144 B
  short*    hbX   = (short*)(ws + 34865152);            //  2,097,152 B (8 xcd x 2 parity x 128 KB)
  short*    rhbX  = (short*)(ws + 36962304);            //  2,097,152 B
  unsigned* flags = (unsigned*)(ws + 39059456);         //     66,560 B

  prep_wxt_k<<<6144, 256, 0, stream>>>(Wz, Wr, Wh, WxT);
  prep_uswz_k<<<1536, 256, 0, stream>>>(Wz, Wr, Wh, Us);
  init_h_k<<<256, 256, 0, stream>>>(h0, h32);

  for (int c = 0; c < NCH; c++) {
    gemm_k<<<dim3(SCH, 48), 256, 0, stream>>>(x, WxT, bz, br, bh, Gx, c * SCH);
    hipMemsetAsync(flags, 0, 66560, stream);
    rec_k<<<256, 256, 0, stream>>>(Gx, Us, h32, hbX, rhbX, flags);
  }
  out_k<<<BB, 64, 0, stream>>>(h32, Wfc, bfc, out);
}